// Round 11
// baseline (235.372 us; speedup 1.0000x reference)
//
#include <hip/hip_runtime.h>
#include <hip/hip_bf16.h>

// Problem constants (from reference)
#define N_USERS    150000
#define N_ENTITIES 250000
#define CHN        64
#define N_RELM1    16
#define N_FACTORS  4
#define N_EDGES    1000000
#define NNZ_       1000000
#define NRECS      (N_EDGES + NNZ_)

// fixed-capacity bucket decomposition (row-space: entities [0,250000), users [USR0, USR0+150000))
#define BROWS      1024
#define RCAP       8192                       // binned-region capacity per bucket (u64 records)
#define RCAP_OUT   8192                       // output recsE/recsU region capacity per bucket
#define EBUCKETS   245                        // ceil(250000/1024)
#define USR0       (EBUCKETS * BROWS)         // 250880
#define ROWS_EFF   (USR0 + N_USERS)           // 400880
#define NB         392                        // ceil(ROWS_EFF/1024)
#define NSLOTS     (NB * BROWS)               // 401408 perm slots
#define TILE_A     4096
#define TA_THREADS 512
#define ITEMS_A    8
#define BIN_BLOCKS 489                        // ceil(NRECS / TILE_A)
#define CONV_N4    (N_ENTITIES * CHN / 4)     // 4,000,000 float4 groups
#define CONV_BLOCKS ((CONV_N4 + 511) / 512)   // 7813

typedef float vf4 __attribute__((ext_vector_type(4)));   // Clang vector: ok for nontemporal builtins

__device__ __forceinline__ unsigned short f2bf(float f) {
    unsigned u = __float_as_uint(f);
    return (unsigned short)((u + 0x7fffu + ((u >> 16) & 1u)) >> 16);  // RNE
}

// -------------------- fused build: bin_pass + prep + bf16 conv --------------------
// Record u64: rowlo(10b)<<50 | payload(50b).
//   entity payload: (rel 4b)<<18 | tail 18b
//   user payload:   (val f32)<<18 | col 18b
__global__ __launch_bounds__(512) void build_kernel(
    const int* __restrict__ head, const int* __restrict__ tail,
    const int* __restrict__ etype, const int* __restrict__ irow,
    const int* __restrict__ icol, const float* __restrict__ val,
    int* __restrict__ bcur, unsigned long long* __restrict__ binned,
    const float* __restrict__ weight, const float* __restrict__ att,
    float* __restrict__ disenw, float* __restrict__ cor_out,
    const float4* __restrict__ esrc, ushort4* __restrict__ ebf0)
{
    int blk = blockIdx.x;
    int tid = threadIdx.x;

    if (blk < BIN_BLOCKS) {
        __shared__ int cntS[NB], startS[NB], gbase[NB];
        __shared__ unsigned long long buf[TILE_A];
        __shared__ unsigned short bk[TILE_A];

        if (tid < NB) cntS[tid] = 0;
        __syncthreads();

        int base = blk * TILE_A;
        unsigned long long p[ITEMS_A];
        int bkt[ITEMS_A], rnk[ITEMS_A];
        #pragma unroll
        for (int j = 0; j < ITEMS_A; ++j) {
            int i = base + j * TA_THREADS + tid;
            bkt[j] = -1;
            if (i < NRECS) {
                int row; unsigned long long pay;
                if (i < N_EDGES) {
                    row = head[i];
                    pay = ((unsigned long long)(unsigned)(etype[i] - 1) << 18) | (unsigned)tail[i];
                } else {
                    int jj = i - N_EDGES;
                    row = USR0 + irow[jj];
                    pay = ((unsigned long long)__float_as_uint(val[jj]) << 18) | (unsigned)icol[jj];
                }
                p[j] = pay | ((unsigned long long)(unsigned)(row & (BROWS - 1)) << 50);
                bkt[j] = row >> 10;
                rnk[j] = atomicAdd(&cntS[bkt[j]], 1);
            }
        }
        __syncthreads();
        if (tid == 0) {
            int s = 0;
            for (int b = 0; b < NB; ++b) { startS[b] = s; s += cntS[b]; }
        }
        __syncthreads();
        if (tid < NB && cntS[tid] > 0)
            gbase[tid] = tid * RCAP + atomicAdd(&bcur[tid], cntS[tid]);
        __syncthreads();

        #pragma unroll
        for (int j = 0; j < ITEMS_A; ++j) {
            if (bkt[j] >= 0) {
                int s = startS[bkt[j]] + rnk[j];
                buf[s] = p[j];
                bk[s] = (unsigned short)bkt[j];
            }
        }
        __syncthreads();

        int total = startS[NB - 1] + cntS[NB - 1];
        for (int s = tid; s < total; s += TA_THREADS) {
            int b = bk[s];
            int dst = gbase[b] + (s - startS[b]);
            if (dst < (b + 1) * RCAP) binned[dst] = buf[s];   // overflow guard (never triggers)
        }
    } else if (blk == BIN_BLOCKS) {
        // ---- prep: disenw + cor ----
        if (tid < 256) {
            int f  = tid >> 6;
            int ch = tid & 63;
            float m = -1e30f;
            for (int r = 0; r < N_RELM1; ++r) m = fmaxf(m, att[f * N_RELM1 + r]);
            float ex[N_RELM1];
            float s = 0.f;
            for (int r = 0; r < N_RELM1; ++r) { ex[r] = expf(att[f * N_RELM1 + r] - m); s += ex[r]; }
            float inv = 1.f / s;
            float acc = 0.f;
            for (int r = 0; r < N_RELM1; ++r) acc += (ex[r] * inv) * weight[r * CHN + ch];
            disenw[f * CHN + ch] = acc;
        }
        if (tid == 0) {
            float wn[N_FACTORS][N_RELM1];
            for (int i = 0; i < N_FACTORS; ++i) {
                float ss = 0.f;
                for (int r = 0; r < N_RELM1; ++r) { float v = att[i * N_RELM1 + r]; ss += v * v; }
                float innv = 1.f / sqrtf(ss);
                for (int r = 0; r < N_RELM1; ++r) wn[i][r] = att[i * N_RELM1 + r] * innv;
            }
            float cor = 0.f;
            for (int i = 0; i < N_FACTORS; ++i)
                for (int j = i + 1; j < N_FACTORS; ++j) {
                    float d = 0.f;
                    for (int r = 0; r < N_RELM1; ++r) d += wn[i][r] * wn[j][r];
                    cor += d * d;
                }
            cor_out[0] = cor;
        }
    } else {
        // ---- bf16 conversion of entity table ----
        int i = (blk - BIN_BLOCKS - 1) * 512 + tid;
        if (i < CONV_N4) {
            float4 v = esrc[i];
            ebf0[i] = make_ushort4(f2bf(v.x), f2bf(v.y), f2bf(v.z), f2bf(v.w));
        }
    }
}

// -------------------- Pass B: per-bucket local CSR + headers + degree-sorted perm ----
// headerE[row] = {cnt<<22|offs, rec0, rec1, rec2}
// headerU[row] = {cnt<<22|offs, rec0.lo, rec0.hi, 0}
// perm[b*BROWS + pos] = unified row id, degree-sorted within bucket (0xFFFFFFFF = pad row)
__global__ __launch_bounds__(512) void bucket_scatter_kernel(
    const unsigned long long* __restrict__ binned,
    const int* __restrict__ bcur,
    unsigned int* __restrict__ recsE,
    unsigned long long* __restrict__ recsU,
    uint4* __restrict__ headerE,
    uint4* __restrict__ headerU,
    unsigned int* __restrict__ perm)
{
    __shared__ int rowcnt[BROWS];
    __shared__ int sExcl[BROWS];
    __shared__ int sA[512], sB[512];
    __shared__ unsigned int hdr0[BROWS], hdr1[BROWS], hdr2[BROWS];
    __shared__ int dh[64], dhoff[64];

    int tid = threadIdx.x;
    int b = blockIdx.x;
    rowcnt[2 * tid] = 0;
    rowcnt[2 * tid + 1] = 0;
    hdr0[2 * tid] = 0; hdr0[2 * tid + 1] = 0;
    hdr1[2 * tid] = 0; hdr1[2 * tid + 1] = 0;
    hdr2[2 * tid] = 0; hdr2[2 * tid + 1] = 0;
    if (tid < 64) dh[tid] = 0;
    __syncthreads();

    int s0 = b * RCAP;
    int nrec = bcur[b];
    if (nrec > RCAP) nrec = RCAP;
    int s1 = s0 + nrec;

    // pass 1: per-row counts
    for (int i = s0 + tid; i < s1; i += 512) {
        int rowlo = (int)(binned[i] >> 50) & (BROWS - 1);
        atomicAdd(&rowcnt[rowlo], 1);
    }
    __syncthreads();

    int c0 = rowcnt[2 * tid];
    int c1 = rowcnt[2 * tid + 1];
    int pc0 = (c0 + 1) & ~1;               // pad to even
    int pc1 = (c1 + 1) & ~1;
    sA[tid] = pc0 + pc1;
    __syncthreads();
    int* src = sA; int* dst = sB;
    #pragma unroll
    for (int off = 1; off < 512; off <<= 1) {
        dst[tid] = src[tid] + ((tid >= off) ? src[tid - off] : 0);
        __syncthreads();
        int* tm = src; src = dst; dst = tm;
    }
    int excl = src[tid] - (pc0 + pc1);

    int gbaseOut = (b < EBUCKETS ? b : b - EBUCKETS) * RCAP_OUT;
    __syncthreads();
    rowcnt[2 * tid] = excl;                 // bucket-local cursors
    rowcnt[2 * tid + 1] = excl + pc0;
    sExcl[2 * tid] = excl;
    sExcl[2 * tid + 1] = excl + pc0;

    // ---- degree-sorted permutation (counting sort over 64 degree bins) ----
    int grow = b * BROWS;
    bool v0, v1;
    if (b < EBUCKETS) { v0 = (grow + 2 * tid) < N_ENTITIES; v1 = (grow + 2 * tid + 1) < N_ENTITIES; }
    else              { v0 = (grow + 2 * tid) < ROWS_EFF;   v1 = (grow + 2 * tid + 1) < ROWS_EFF; }
    int key0 = v0 ? min(c0, 63) : 0;
    int key1 = v1 ? min(c1, 63) : 0;
    int rank0 = atomicAdd(&dh[key0], 1);
    int rank1 = atomicAdd(&dh[key1], 1);
    __syncthreads();
    if (tid == 0) {
        int s = 0;
        #pragma unroll
        for (int i = 0; i < 64; ++i) { dhoff[i] = s; s += dh[i]; }
    }
    __syncthreads();
    perm[grow + dhoff[key0] + rank0] = v0 ? (unsigned)(grow + 2 * tid)     : 0xFFFFFFFFu;
    perm[grow + dhoff[key1] + rank1] = v1 ? (unsigned)(grow + 2 * tid + 1) : 0xFFFFFFFFu;
    __syncthreads();

    // pass 2: scatter to final slots; capture first records for the header
    if (b < EBUCKETS) {
        for (int i = s0 + tid; i < s1; i += 512) {
            unsigned long long p = binned[i];
            int rowlo = (int)(p >> 50) & (BROWS - 1);
            int local = atomicAdd(&rowcnt[rowlo], 1);
            unsigned rec = (unsigned)(p & ((1ull << 50) - 1));
            recsE[gbaseOut + local] = rec;
            int rank = local - sExcl[rowlo];
            if (rank == 0) hdr0[rowlo] = rec;
            else if (rank == 1) hdr1[rowlo] = rec;
            else if (rank == 2) hdr2[rowlo] = rec;
        }
        __syncthreads();
        #pragma unroll
        for (int t = 0; t < 2; ++t) {
            int r = 2 * tid + t;
            int row = grow + r;
            if (row < N_ENTITIES) {
                unsigned co = ((unsigned)((t == 0) ? c0 : c1) << 22) |
                              (unsigned)(gbaseOut + sExcl[r]);
                headerE[row] = make_uint4(co, hdr0[r], hdr1[r], hdr2[r]);
            }
        }
    } else {
        for (int i = s0 + tid; i < s1; i += 512) {
            unsigned long long p = binned[i];
            int rowlo = (int)(p >> 50) & (BROWS - 1);
            int local = atomicAdd(&rowcnt[rowlo], 1);
            unsigned long long rec = p & ((1ull << 50) - 1);
            recsU[gbaseOut + local] = rec;
            int rank = local - sExcl[rowlo];
            if (rank == 0) { hdr0[rowlo] = (unsigned)rec; hdr1[rowlo] = (unsigned)(rec >> 32); }
        }
        __syncthreads();
        int ubase = grow - USR0;
        #pragma unroll
        for (int t = 0; t < 2; ++t) {
            int r = 2 * tid + t;
            int urow = ubase + r;
            if (urow >= 0 && urow < N_USERS) {
                unsigned co = ((unsigned)((t == 0) ? c0 : c1) << 22) |
                              (unsigned)(gbaseOut + sExcl[r]);
                headerU[urow] = make_uint4(co, hdr0[r], hdr1[r], 0u);
            }
        }
    }
}

// -------------------- fused hop: 8 lanes per row, 8 bf16 (uint4) per lane ------------
__device__ __forceinline__ void fma8w(uint4 g, const float* __restrict__ w, float* acc) {
    acc[0] += __uint_as_float(g.x << 16)          * w[0];
    acc[1] += __uint_as_float(g.x & 0xffff0000u)  * w[1];
    acc[2] += __uint_as_float(g.y << 16)          * w[2];
    acc[3] += __uint_as_float(g.y & 0xffff0000u)  * w[3];
    acc[4] += __uint_as_float(g.z << 16)          * w[4];
    acc[5] += __uint_as_float(g.z & 0xffff0000u)  * w[5];
    acc[6] += __uint_as_float(g.w << 16)          * w[6];
    acc[7] += __uint_as_float(g.w & 0xffff0000u)  * w[7];
}
__device__ __forceinline__ void fma8v(uint4 g, float v, float* acc) {
    acc[0] += __uint_as_float(g.x << 16)          * v;
    acc[1] += __uint_as_float(g.x & 0xffff0000u)  * v;
    acc[2] += __uint_as_float(g.y << 16)          * v;
    acc[3] += __uint_as_float(g.y & 0xffff0000u)  * v;
    acc[4] += __uint_as_float(g.z << 16)          * v;
    acc[5] += __uint_as_float(g.z & 0xffff0000u)  * v;
    acc[6] += __uint_as_float(g.w << 16)          * v;
    acc[7] += __uint_as_float(g.w & 0xffff0000u)  * v;
}
__device__ __forceinline__ void bf8_unpack(uint4 g, float* o) {
    o[0] = __uint_as_float(g.x << 16); o[1] = __uint_as_float(g.x & 0xffff0000u);
    o[2] = __uint_as_float(g.y << 16); o[3] = __uint_as_float(g.y & 0xffff0000u);
    o[4] = __uint_as_float(g.z << 16); o[5] = __uint_as_float(g.z & 0xffff0000u);
    o[6] = __uint_as_float(g.w << 16); o[7] = __uint_as_float(g.w & 0xffff0000u);
}

// PASS 1: gather from ebf0 -> write compact bf16 state only (ebfA, ubfA).
// PASS 2: gather from ebfA -> out = emb(f32) + y1(bf16, own-row) + y2.
template<int PASS>
__global__ __launch_bounds__(256) void hop_kernel(
    const unsigned short* __restrict__ ebf,     // gather table (pass1: ebf0, pass2: ebfA)
    const unsigned int* __restrict__ recsE,
    const unsigned long long* __restrict__ recsU,
    const uint4* __restrict__ headerE,
    const uint4* __restrict__ headerU,
    const unsigned int* __restrict__ perm,      // degree-sorted row order
    const float* __restrict__ weight,           // [16][64] f32
    const float* __restrict__ latent,           // [4][64]
    const float* __restrict__ disenw,           // [4][64]
    const float* __restrict__ u_emb,            // user_emb f32 (pass1: softmax src; pass2: base)
    const float* __restrict__ e_emb,            // entity_emb f32 (pass2 base)
    const unsigned short* __restrict__ ubfA,    // pass2: u1 bf16 (softmax src + residual term)
    unsigned short* __restrict__ ebf_new,       // pass1 out
    unsigned short* __restrict__ ubf_new,       // pass1 out
    float* __restrict__ out_ent,                // pass2 out
    float* __restrict__ out_usr)                // pass2 out
{
    __shared__ float wl[N_RELM1 * CHN];
    for (int k = threadIdx.x; k < N_RELM1 * CHN; k += 256) wl[k] = weight[k];
    __syncthreads();

    unsigned idx = blockIdx.x * 256u + threadIdx.x;
    unsigned slot = idx >> 3;         // 8 lanes per row
    int sub = idx & 7;                // channels [sub*8, sub*8+8)
    int chb = sub * 8;
    if (slot >= NSLOTS) return;
    unsigned row = perm[slot];

    float acc[8] = {0.f,0.f,0.f,0.f,0.f,0.f,0.f,0.f};

    if (row < N_ENTITIES) {
        uint4 h = headerE[row];
        int n = h.x >> 22;
        int start = h.x & 0x3FFFFF;
        // inline records: gathers issue right after the header arrives
        if (n > 0) {
            uint4 g = *(const uint4*)(ebf + (size_t)(h.y & 0x3FFFF) * CHN + chb);
            fma8w(g, &wl[(h.y >> 18) * CHN + chb], acc);
        }
        if (n > 1) {
            uint4 g = *(const uint4*)(ebf + (size_t)(h.z & 0x3FFFF) * CHN + chb);
            fma8w(g, &wl[(h.z >> 18) * CHN + chb], acc);
        }
        if (n > 2) {
            uint4 g = *(const uint4*)(ebf + (size_t)(h.w & 0x3FFFF) * CHN + chb);
            fma8w(g, &wl[(h.w >> 18) * CHN + chb], acc);
        }
        int k = 3;
        for (; k + 4 <= n; k += 4) {
            unsigned r0 = recsE[start + k];
            unsigned r1 = recsE[start + k + 1];
            unsigned r2 = recsE[start + k + 2];
            unsigned r3 = recsE[start + k + 3];
            uint4 g0 = *(const uint4*)(ebf + (size_t)(r0 & 0x3FFFF) * CHN + chb);
            uint4 g1 = *(const uint4*)(ebf + (size_t)(r1 & 0x3FFFF) * CHN + chb);
            uint4 g2 = *(const uint4*)(ebf + (size_t)(r2 & 0x3FFFF) * CHN + chb);
            uint4 g3 = *(const uint4*)(ebf + (size_t)(r3 & 0x3FFFF) * CHN + chb);
            fma8w(g0, &wl[(r0 >> 18) * CHN + chb], acc);
            fma8w(g1, &wl[(r1 >> 18) * CHN + chb], acc);
            fma8w(g2, &wl[(r2 >> 18) * CHN + chb], acc);
            fma8w(g3, &wl[(r3 >> 18) * CHN + chb], acc);
        }
        for (; k < n; ++k) {
            unsigned r0 = recsE[start + k];
            uint4 g0 = *(const uint4*)(ebf + (size_t)(r0 & 0x3FFFF) * CHN + chb);
            fma8w(g0, &wl[(r0 >> 18) * CHN + chb], acc);
        }
        float inv_d = (n > 0) ? (1.f / (float)n) : 1.f;
        float ss = 0.f;
        #pragma unroll
        for (int i = 0; i < 8; ++i) { acc[i] *= inv_d; ss += acc[i] * acc[i]; }
        ss += __shfl_xor(ss, 1, 64);
        ss += __shfl_xor(ss, 2, 64);
        ss += __shfl_xor(ss, 4, 64);
        float innv = 1.f / fmaxf(sqrtf(ss), 1e-12f);
        float y[8];
        #pragma unroll
        for (int i = 0; i < 8; ++i) y[i] = acc[i] * innv;
        if (PASS == 1) {
            uint4 pk;
            pk.x = (unsigned)f2bf(y[0]) | ((unsigned)f2bf(y[1]) << 16);
            pk.y = (unsigned)f2bf(y[2]) | ((unsigned)f2bf(y[3]) << 16);
            pk.z = (unsigned)f2bf(y[4]) | ((unsigned)f2bf(y[5]) << 16);
            pk.w = (unsigned)f2bf(y[6]) | ((unsigned)f2bf(y[7]) << 16);
            *(uint4*)(ebf_new + (size_t)row * CHN + chb) = pk;
        } else {
            float y1[8];
            bf8_unpack(*(const uint4*)(ebf + (size_t)row * CHN + chb), y1);  // own hop-1 value
            const vf4* bp = (const vf4*)&e_emb[(size_t)row * CHN + chb];
            vf4 b0 = __builtin_nontemporal_load(bp);
            vf4 b1 = __builtin_nontemporal_load(bp + 1);
            vf4* op = (vf4*)&out_ent[(size_t)row * CHN + chb];
            vf4 o0 = {b0.x + y1[0] + y[0], b0.y + y1[1] + y[1], b0.z + y1[2] + y[2], b0.w + y1[3] + y[3]};
            vf4 o1 = {b1.x + y1[4] + y[4], b1.y + y1[5] + y[5], b1.z + y1[6] + y[6], b1.w + y1[7] + y[7]};
            __builtin_nontemporal_store(o0, op);
            __builtin_nontemporal_store(o1, op + 1);
        }
    } else if (row < ROWS_EFF) {
        unsigned ur = row - USR0;
        uint4 h = headerU[ur];
        int n = h.x >> 22;
        int start = h.x & 0x3FFFFF;

        // inline record 0 gathers immediately
        if (n > 0) {
            unsigned long long q = ((unsigned long long)h.z << 32) | h.y;
            uint4 g = *(const uint4*)(ebf + (size_t)(q & 0x3FFFFu) * CHN + chb);
            fma8v(g, __uint_as_float((unsigned)(q >> 18)), acc);
        }
        int k = 1;
        for (; k + 4 <= n; k += 4) {
            unsigned long long q0 = recsU[start + k];
            unsigned long long q1 = recsU[start + k + 1];
            unsigned long long q2 = recsU[start + k + 2];
            unsigned long long q3 = recsU[start + k + 3];
            uint4 g0 = *(const uint4*)(ebf + (size_t)(q0 & 0x3FFFFu) * CHN + chb);
            uint4 g1 = *(const uint4*)(ebf + (size_t)(q1 & 0x3FFFFu) * CHN + chb);
            uint4 g2 = *(const uint4*)(ebf + (size_t)(q2 & 0x3FFFFu) * CHN + chb);
            uint4 g3 = *(const uint4*)(ebf + (size_t)(q3 & 0x3FFFFu) * CHN + chb);
            fma8v(g0, __uint_as_float((unsigned)(q0 >> 18)), acc);
            fma8v(g1, __uint_as_float((unsigned)(q1 >> 18)), acc);
            fma8v(g2, __uint_as_float((unsigned)(q2 >> 18)), acc);
            fma8v(g3, __uint_as_float((unsigned)(q3 >> 18)), acc);
        }
        for (; k < n; ++k) {
            unsigned long long q0 = recsU[start + k];
            uint4 g0 = *(const uint4*)(ebf + (size_t)(q0 & 0x3FFFFu) * CHN + chb);
            fma8v(g0, __uint_as_float((unsigned)(q0 >> 18)), acc);
        }

        float uo[8];
        if (PASS == 1) {
            const float4* up = (const float4*)&u_emb[(size_t)ur * CHN + chb];
            float4 a0 = up[0], a1 = up[1];
            uo[0]=a0.x; uo[1]=a0.y; uo[2]=a0.z; uo[3]=a0.w;
            uo[4]=a1.x; uo[5]=a1.y; uo[6]=a1.z; uo[7]=a1.w;
        } else {
            bf8_unpack(*(const uint4*)(ubfA + (size_t)ur * CHN + chb), uo);
        }

        float dotv[N_FACTORS];
        #pragma unroll
        for (int f = 0; f < N_FACTORS; ++f) {
            const float4* lp = (const float4*)&latent[f * CHN + chb];
            float4 l0 = lp[0], l1 = lp[1];
            float p = uo[0] * l0.x + uo[1] * l0.y + uo[2] * l0.z + uo[3] * l0.w
                    + uo[4] * l1.x + uo[5] * l1.y + uo[6] * l1.z + uo[7] * l1.w;
            p += __shfl_xor(p, 1, 64);
            p += __shfl_xor(p, 2, 64);
            p += __shfl_xor(p, 4, 64);
            dotv[f] = p;
        }
        float m = fmaxf(fmaxf(dotv[0], dotv[1]), fmaxf(dotv[2], dotv[3]));
        float es = 0.f;
        #pragma unroll
        for (int f = 0; f < N_FACTORS; ++f) { dotv[f] = expf(dotv[f] - m); es += dotv[f]; }
        float sinv = 1.f / es;
        float mix[8] = {0.f,0.f,0.f,0.f,0.f,0.f,0.f,0.f};
        #pragma unroll
        for (int f = 0; f < N_FACTORS; ++f) {
            float sc = dotv[f] * sinv;
            const float4* dp = (const float4*)&disenw[f * CHN + chb];
            float4 d0 = dp[0], d1 = dp[1];
            mix[0] += sc * d0.x; mix[1] += sc * d0.y; mix[2] += sc * d0.z; mix[3] += sc * d0.w;
            mix[4] += sc * d1.x; mix[5] += sc * d1.y; mix[6] += sc * d1.z; mix[7] += sc * d1.w;
        }

        float ss = 0.f;
        #pragma unroll
        for (int i = 0; i < 8; ++i) { acc[i] *= (1.f + mix[i]); ss += acc[i] * acc[i]; }
        ss += __shfl_xor(ss, 1, 64);
        ss += __shfl_xor(ss, 2, 64);
        ss += __shfl_xor(ss, 4, 64);
        float innv = 1.f / fmaxf(sqrtf(ss), 1e-12f);
        float y[8];
        #pragma unroll
        for (int i = 0; i < 8; ++i) y[i] = acc[i] * innv;
        if (PASS == 1) {
            uint4 pk;
            pk.x = (unsigned)f2bf(y[0]) | ((unsigned)f2bf(y[1]) << 16);
            pk.y = (unsigned)f2bf(y[2]) | ((unsigned)f2bf(y[3]) << 16);
            pk.z = (unsigned)f2bf(y[4]) | ((unsigned)f2bf(y[5]) << 16);
            pk.w = (unsigned)f2bf(y[6]) | ((unsigned)f2bf(y[7]) << 16);
            *(uint4*)(ubf_new + (size_t)ur * CHN + chb) = pk;
        } else {
            const vf4* bp = (const vf4*)&u_emb[(size_t)ur * CHN + chb];
            vf4 b0 = __builtin_nontemporal_load(bp);
            vf4 b1 = __builtin_nontemporal_load(bp + 1);
            vf4* op = (vf4*)&out_usr[(size_t)ur * CHN + chb];
            vf4 o0 = {b0.x + uo[0] + y[0], b0.y + uo[1] + y[1], b0.z + uo[2] + y[2], b0.w + uo[3] + y[3]};
            vf4 o1 = {b1.x + uo[4] + y[4], b1.y + uo[5] + y[5], b1.z + uo[6] + y[6], b1.w + uo[7] + y[7]};
            __builtin_nontemporal_store(o0, op);
            __builtin_nontemporal_store(o1, op + 1);
        }
    }
}

extern "C" void kernel_launch(void* const* d_in, const int* in_sizes, int n_in,
                              void* d_out, int out_size, void* d_ws, size_t ws_size,
                              hipStream_t stream) {
    const float* user_emb   = (const float*)d_in[0];
    const float* entity_emb = (const float*)d_in[1];
    const float* latent_emb = (const float*)d_in[2];
    const float* weight     = (const float*)d_in[3];
    const float* att        = (const float*)d_in[4];
    const float* inter_val  = (const float*)d_in[5];
    const int*   edge_index = (const int*)d_in[6];   // [2][N_EDGES]
    const int*   edge_type  = (const int*)d_in[7];
    const int*   inter_row  = (const int*)d_in[8];
    const int*   inter_col  = (const int*)d_in[9];

    const int* head = edge_index;
    const int* tail = edge_index + N_EDGES;

    float* out_ent = (float*)d_out;                              // [250000*64]
    float* out_usr = out_ent + (size_t)N_ENTITIES * CHN;         // [150000*64]
    float* out_cor = out_usr + (size_t)N_USERS * CHN;            // [1]

    // workspace layout (byte offsets kept 16B-aligned)
    char* ws = (char*)d_ws;
    unsigned short* ebf0   = (unsigned short*)ws;                             // 32,000,000 B
    unsigned short* ebfA   = (unsigned short*)(ws + 32000000);                // 32,000,000 B
    unsigned short* ubfA   = (unsigned short*)(ws + 64000000);                // 19,200,000 B
    unsigned long long* binned = (unsigned long long*)(ws + 83200000);        // NB*RCAP u64 = 25,690,112 B
    unsigned long long* recsU  = (unsigned long long*)(ws + 108890112);       // 147*RCAP_OUT u64 = 9,633,792 B
    unsigned int* recsE    = (unsigned int*)(ws + 118523904);                 // 245*RCAP_OUT u32 = 8,028,160 B
    float* disenw          = (float*)(ws + 126552064);                        // 1,024 B
    uint4* headerE         = (uint4*)(ws + 126553088);                        // 250000*16 = 4,000,000 B
    uint4* headerU         = (uint4*)(ws + 130553088);                        // 150000*16 = 2,400,000 B
    unsigned int* perm     = (unsigned int*)(ws + 132953088);                 // NSLOTS u32 = 1,605,632 B
    int*   bcur            = (int*)(ws + 134558720);                          // NB i

    // ---- bucket cursors = 0 (offset-from-base scheme) ----
    hipMemsetAsync(bcur, 0, NB * sizeof(int), stream);

    // ---- fused build: bin_pass + prep + bf16 conv ----
    build_kernel<<<BIN_BLOCKS + 1 + CONV_BLOCKS, 512, 0, stream>>>(
        head, tail, edge_type, inter_row, inter_col, inter_val,
        bcur, binned, weight, att, disenw, out_cor,
        (const float4*)entity_emb, (ushort4*)ebf0);

    // ---- per-bucket CSR + headers + degree-sorted perm ----
    bucket_scatter_kernel<<<NB, 512, 0, stream>>>(binned, bcur, recsE, recsU,
                                                  headerE, headerU, perm);

    const int hop_blocks = (NSLOTS * 8) / 256;                   // 12544

    // ---- hop 1: gather from ebf0 -> compact bf16 state (ebfA, ubfA) ----
    hop_kernel<1><<<hop_blocks, 256, 0, stream>>>(ebf0, recsE, recsU, headerE, headerU, perm,
                                                  weight, latent_emb, disenw,
                                                  user_emb, entity_emb, nullptr,
                                                  ebfA, ubfA, nullptr, nullptr);

    // ---- hop 2: gather from ebfA -> out = emb + y1 + y2 ----
    hop_kernel<2><<<hop_blocks, 256, 0, stream>>>(ebfA, recsE, recsU, headerE, headerU, perm,
                                                  weight, latent_emb, disenw,
                                                  user_emb, entity_emb, ubfA,
                                                  nullptr, nullptr, out_ent, out_usr);
}

// Round 12
// 213.870 us; speedup vs baseline: 1.1005x; 1.1005x over previous
//
#include <hip/hip_runtime.h>
#include <hip/hip_bf16.h>

// Problem constants (from reference)
#define N_USERS    150000
#define N_ENTITIES 250000
#define CHN        64
#define N_RELM1    16
#define N_FACTORS  4
#define N_EDGES    1000000
#define NNZ_       1000000
#define NRECS      (N_EDGES + NNZ_)

// fixed-capacity bucket decomposition (row-space: entities [0,250000), users [USR0, USR0+150000))
#define BROWS      1024
#define RCAP       8192                       // binned-region capacity per bucket (u64 records)
#define RCAP_OUT   8192                       // output recsE/recsU region capacity per bucket
#define EBUCKETS   245                        // ceil(250000/1024)
#define USR0       (EBUCKETS * BROWS)         // 250880
#define ROWS_EFF   (USR0 + N_USERS)           // 400880
#define NB         392                        // ceil(ROWS_EFF/1024)
#define TILE_A     4096
#define TA_THREADS 512
#define ITEMS_A    8
#define BIN_BLOCKS 489                        // ceil(NRECS / TILE_A)
#define CONV_N4    (N_ENTITIES * CHN / 4)     // 4,000,000 float4 groups
#define CONV_BLOCKS ((CONV_N4 + 511) / 512)   // 7813

typedef float vf4 __attribute__((ext_vector_type(4)));   // Clang vector: ok for nontemporal builtins

__device__ __forceinline__ unsigned short f2bf(float f) {
    unsigned u = __float_as_uint(f);
    return (unsigned short)((u + 0x7fffu + ((u >> 16) & 1u)) >> 16);  // RNE
}

// -------------------- fused build: bin_pass + prep + bf16 conv --------------------
// Record u64: rowlo(10b)<<50 | payload(50b).
//   entity payload: (rel 4b)<<18 | tail 18b
//   user payload:   (val f32)<<18 | col 18b
__global__ __launch_bounds__(512) void build_kernel(
    const int* __restrict__ head, const int* __restrict__ tail,
    const int* __restrict__ etype, const int* __restrict__ irow,
    const int* __restrict__ icol, const float* __restrict__ val,
    int* __restrict__ bcur, unsigned long long* __restrict__ binned,
    const float* __restrict__ weight, const float* __restrict__ att,
    float* __restrict__ disenw, float* __restrict__ cor_out,
    const float4* __restrict__ esrc, ushort4* __restrict__ ebf0)
{
    int blk = blockIdx.x;
    int tid = threadIdx.x;

    if (blk < BIN_BLOCKS) {
        __shared__ int cntS[NB], startS[NB], gbase[NB];
        __shared__ unsigned long long buf[TILE_A];
        __shared__ unsigned short bk[TILE_A];

        if (tid < NB) cntS[tid] = 0;
        __syncthreads();

        int base = blk * TILE_A;
        unsigned long long p[ITEMS_A];
        int bkt[ITEMS_A], rnk[ITEMS_A];
        #pragma unroll
        for (int j = 0; j < ITEMS_A; ++j) {
            int i = base + j * TA_THREADS + tid;
            bkt[j] = -1;
            if (i < NRECS) {
                int row; unsigned long long pay;
                if (i < N_EDGES) {
                    row = head[i];
                    pay = ((unsigned long long)(unsigned)(etype[i] - 1) << 18) | (unsigned)tail[i];
                } else {
                    int jj = i - N_EDGES;
                    row = USR0 + irow[jj];
                    pay = ((unsigned long long)__float_as_uint(val[jj]) << 18) | (unsigned)icol[jj];
                }
                p[j] = pay | ((unsigned long long)(unsigned)(row & (BROWS - 1)) << 50);
                bkt[j] = row >> 10;
                rnk[j] = atomicAdd(&cntS[bkt[j]], 1);
            }
        }
        __syncthreads();
        if (tid == 0) {
            int s = 0;
            for (int b = 0; b < NB; ++b) { startS[b] = s; s += cntS[b]; }
        }
        __syncthreads();
        if (tid < NB && cntS[tid] > 0)
            gbase[tid] = tid * RCAP + atomicAdd(&bcur[tid], cntS[tid]);
        __syncthreads();

        #pragma unroll
        for (int j = 0; j < ITEMS_A; ++j) {
            if (bkt[j] >= 0) {
                int s = startS[bkt[j]] + rnk[j];
                buf[s] = p[j];
                bk[s] = (unsigned short)bkt[j];
            }
        }
        __syncthreads();

        int total = startS[NB - 1] + cntS[NB - 1];
        for (int s = tid; s < total; s += TA_THREADS) {
            int b = bk[s];
            int dst = gbase[b] + (s - startS[b]);
            if (dst < (b + 1) * RCAP) binned[dst] = buf[s];   // overflow guard (never triggers)
        }
    } else if (blk == BIN_BLOCKS) {
        // ---- prep: disenw + cor ----
        if (tid < 256) {
            int f  = tid >> 6;
            int ch = tid & 63;
            float m = -1e30f;
            for (int r = 0; r < N_RELM1; ++r) m = fmaxf(m, att[f * N_RELM1 + r]);
            float ex[N_RELM1];
            float s = 0.f;
            for (int r = 0; r < N_RELM1; ++r) { ex[r] = expf(att[f * N_RELM1 + r] - m); s += ex[r]; }
            float inv = 1.f / s;
            float acc = 0.f;
            for (int r = 0; r < N_RELM1; ++r) acc += (ex[r] * inv) * weight[r * CHN + ch];
            disenw[f * CHN + ch] = acc;
        }
        if (tid == 0) {
            float wn[N_FACTORS][N_RELM1];
            for (int i = 0; i < N_FACTORS; ++i) {
                float ss = 0.f;
                for (int r = 0; r < N_RELM1; ++r) { float v = att[i * N_RELM1 + r]; ss += v * v; }
                float innv = 1.f / sqrtf(ss);
                for (int r = 0; r < N_RELM1; ++r) wn[i][r] = att[i * N_RELM1 + r] * innv;
            }
            float cor = 0.f;
            for (int i = 0; i < N_FACTORS; ++i)
                for (int j = i + 1; j < N_FACTORS; ++j) {
                    float d = 0.f;
                    for (int r = 0; r < N_RELM1; ++r) d += wn[i][r] * wn[j][r];
                    cor += d * d;
                }
            cor_out[0] = cor;
        }
    } else {
        // ---- bf16 conversion of entity table ----
        int i = (blk - BIN_BLOCKS - 1) * 512 + tid;
        if (i < CONV_N4) {
            float4 v = esrc[i];
            ebf0[i] = make_ushort4(f2bf(v.x), f2bf(v.y), f2bf(v.z), f2bf(v.w));
        }
    }
}

// -------------------- Pass B: per-bucket local CSR; emits packed (cnt<<22|offs) ----
__global__ __launch_bounds__(512) void bucket_scatter_kernel(
    const unsigned long long* __restrict__ binned,
    const int* __restrict__ bcur,
    unsigned int* __restrict__ recsE,
    unsigned long long* __restrict__ recsU,
    unsigned int* __restrict__ cntoffs)
{
    __shared__ int rowcnt[BROWS];
    __shared__ int sA[512], sB[512];

    int tid = threadIdx.x;
    int b = blockIdx.x;
    rowcnt[2 * tid] = 0;
    rowcnt[2 * tid + 1] = 0;
    __syncthreads();

    int s0 = b * RCAP;
    int nrec = bcur[b];
    if (nrec > RCAP) nrec = RCAP;
    int s1 = s0 + nrec;

    // pass 1: per-row counts
    for (int i = s0 + tid; i < s1; i += 512) {
        int rowlo = (int)(binned[i] >> 50) & (BROWS - 1);
        atomicAdd(&rowcnt[rowlo], 1);
    }
    __syncthreads();

    int c0 = rowcnt[2 * tid];
    int c1 = rowcnt[2 * tid + 1];
    int pc0 = (c0 + 1) & ~1;               // pad to even
    int pc1 = (c1 + 1) & ~1;
    sA[tid] = pc0 + pc1;
    __syncthreads();
    int* src = sA; int* dst = sB;
    #pragma unroll
    for (int off = 1; off < 512; off <<= 1) {
        dst[tid] = src[tid] + ((tid >= off) ? src[tid - off] : 0);
        __syncthreads();
        int* tm = src; src = dst; dst = tm;
    }
    int excl = src[tid] - (pc0 + pc1);

    int gbaseOut = (b < EBUCKETS ? b : b - EBUCKETS) * RCAP_OUT;
    int grow = b * BROWS;
    cntoffs[grow + 2 * tid]     = ((unsigned)c0 << 22) | (unsigned)(gbaseOut + excl);
    cntoffs[grow + 2 * tid + 1] = ((unsigned)c1 << 22) | (unsigned)(gbaseOut + excl + pc0);
    __syncthreads();
    rowcnt[2 * tid] = excl;                 // repurpose as cursors (bucket-local)
    rowcnt[2 * tid + 1] = excl + pc0;
    __syncthreads();

    // pass 2: scatter to final slots
    if (b < EBUCKETS) {
        for (int i = s0 + tid; i < s1; i += 512) {
            unsigned long long p = binned[i];
            int rowlo = (int)(p >> 50) & (BROWS - 1);
            int local = atomicAdd(&rowcnt[rowlo], 1);
            recsE[gbaseOut + local] = (unsigned)(p & ((1ull << 50) - 1));
        }
    } else {
        for (int i = s0 + tid; i < s1; i += 512) {
            unsigned long long p = binned[i];
            int rowlo = (int)(p >> 50) & (BROWS - 1);
            int local = atomicAdd(&rowcnt[rowlo], 1);
            recsU[gbaseOut + local] = p & ((1ull << 50) - 1);
        }
    }
}

// -------------------- fused hop: 8 lanes per row, 8 bf16 (uint4) per lane ------------
__device__ __forceinline__ void fma8w(uint4 g, const float* __restrict__ w, float* acc) {
    acc[0] += __uint_as_float(g.x << 16)          * w[0];
    acc[1] += __uint_as_float(g.x & 0xffff0000u)  * w[1];
    acc[2] += __uint_as_float(g.y << 16)          * w[2];
    acc[3] += __uint_as_float(g.y & 0xffff0000u)  * w[3];
    acc[4] += __uint_as_float(g.z << 16)          * w[4];
    acc[5] += __uint_as_float(g.z & 0xffff0000u)  * w[5];
    acc[6] += __uint_as_float(g.w << 16)          * w[6];
    acc[7] += __uint_as_float(g.w & 0xffff0000u)  * w[7];
}
__device__ __forceinline__ void fma8v(uint4 g, float v, float* acc) {
    acc[0] += __uint_as_float(g.x << 16)          * v;
    acc[1] += __uint_as_float(g.x & 0xffff0000u)  * v;
    acc[2] += __uint_as_float(g.y << 16)          * v;
    acc[3] += __uint_as_float(g.y & 0xffff0000u)  * v;
    acc[4] += __uint_as_float(g.z << 16)          * v;
    acc[5] += __uint_as_float(g.z & 0xffff0000u)  * v;
    acc[6] += __uint_as_float(g.w << 16)          * v;
    acc[7] += __uint_as_float(g.w & 0xffff0000u)  * v;
}
__device__ __forceinline__ void bf8_unpack(uint4 g, float* o) {
    o[0] = __uint_as_float(g.x << 16); o[1] = __uint_as_float(g.x & 0xffff0000u);
    o[2] = __uint_as_float(g.y << 16); o[3] = __uint_as_float(g.y & 0xffff0000u);
    o[4] = __uint_as_float(g.z << 16); o[5] = __uint_as_float(g.z & 0xffff0000u);
    o[6] = __uint_as_float(g.w << 16); o[7] = __uint_as_float(g.w & 0xffff0000u);
}

// PASS 1: gather from ebf0 -> write compact bf16 state only (ebfA, ubfA).
// PASS 2: gather from ebfA -> out = base(bf16/f32) + y1(bf16, own-row) + y2.
template<int PASS>
__global__ __launch_bounds__(256) void hop_kernel(
    const unsigned short* __restrict__ ebf,     // gather table (pass1: ebf0, pass2: ebfA)
    const unsigned int* __restrict__ recsE,
    const unsigned long long* __restrict__ recsU,
    const unsigned int* __restrict__ cntoffs,
    const float* __restrict__ weight,           // [16][64] f32
    const float* __restrict__ latent,           // [4][64]
    const float* __restrict__ disenw,           // [4][64]
    const float* __restrict__ u_emb,            // user_emb f32 (pass1: softmax src; pass2: base)
    const unsigned short* __restrict__ ebase,   // pass2: entity base, bf16 (ebf0)
    const unsigned short* __restrict__ ubfA,    // pass2: u1 bf16 (softmax src + residual term)
    unsigned short* __restrict__ ebf_new,       // pass1 out
    unsigned short* __restrict__ ubf_new,       // pass1 out
    float* __restrict__ out_ent,                // pass2 out
    float* __restrict__ out_usr)                // pass2 out
{
    __shared__ float wl[N_RELM1 * CHN];
    for (int k = threadIdx.x; k < N_RELM1 * CHN; k += 256) wl[k] = weight[k];
    __syncthreads();

    unsigned idx = blockIdx.x * 256u + threadIdx.x;
    unsigned row = idx >> 3;          // 8 lanes per row
    int sub = idx & 7;                // channels [sub*8, sub*8+8)
    int chb = sub * 8;

    float acc[8] = {0.f,0.f,0.f,0.f,0.f,0.f,0.f,0.f};

    if (row < N_ENTITIES) {
        unsigned co = cntoffs[row];
        int n = co >> 22;
        int start = co & 0x3FFFFF;
        int k = 0;
        for (; k + 4 <= n; k += 4) {
            uint2 ra = *(const uint2*)&recsE[start + k];
            uint2 rb = *(const uint2*)&recsE[start + k + 2];
            uint4 g0 = *(const uint4*)(ebf + (size_t)(ra.x & 0x3FFFF) * CHN + chb);
            uint4 g1 = *(const uint4*)(ebf + (size_t)(ra.y & 0x3FFFF) * CHN + chb);
            uint4 g2 = *(const uint4*)(ebf + (size_t)(rb.x & 0x3FFFF) * CHN + chb);
            uint4 g3 = *(const uint4*)(ebf + (size_t)(rb.y & 0x3FFFF) * CHN + chb);
            fma8w(g0, &wl[(ra.x >> 18) * CHN + chb], acc);
            fma8w(g1, &wl[(ra.y >> 18) * CHN + chb], acc);
            fma8w(g2, &wl[(rb.x >> 18) * CHN + chb], acc);
            fma8w(g3, &wl[(rb.y >> 18) * CHN + chb], acc);
        }
        for (; k < n; ++k) {
            unsigned r0 = recsE[start + k];
            uint4 g0 = *(const uint4*)(ebf + (size_t)(r0 & 0x3FFFF) * CHN + chb);
            fma8w(g0, &wl[(r0 >> 18) * CHN + chb], acc);
        }
        float inv_d = (n > 0) ? (1.f / (float)n) : 1.f;
        float ss = 0.f;
        #pragma unroll
        for (int i = 0; i < 8; ++i) { acc[i] *= inv_d; ss += acc[i] * acc[i]; }
        ss += __shfl_xor(ss, 1, 64);
        ss += __shfl_xor(ss, 2, 64);
        ss += __shfl_xor(ss, 4, 64);
        float innv = 1.f / fmaxf(sqrtf(ss), 1e-12f);
        float y[8];
        #pragma unroll
        for (int i = 0; i < 8; ++i) y[i] = acc[i] * innv;
        if (PASS == 1) {
            uint4 pk;
            pk.x = (unsigned)f2bf(y[0]) | ((unsigned)f2bf(y[1]) << 16);
            pk.y = (unsigned)f2bf(y[2]) | ((unsigned)f2bf(y[3]) << 16);
            pk.z = (unsigned)f2bf(y[4]) | ((unsigned)f2bf(y[5]) << 16);
            pk.w = (unsigned)f2bf(y[6]) | ((unsigned)f2bf(y[7]) << 16);
            *(uint4*)(ebf_new + (size_t)row * CHN + chb) = pk;
        } else {
            float y1[8];
            bf8_unpack(*(const uint4*)(ebf + (size_t)row * CHN + chb), y1);    // own hop-1 value
            float b[8];
            bf8_unpack(*(const uint4*)(ebase + (size_t)row * CHN + chb), b);   // bf16 base (ebf0)
            vf4* op = (vf4*)&out_ent[(size_t)row * CHN + chb];
            vf4 o0 = {b[0] + y1[0] + y[0], b[1] + y1[1] + y[1], b[2] + y1[2] + y[2], b[3] + y1[3] + y[3]};
            vf4 o1 = {b[4] + y1[4] + y[4], b[5] + y1[5] + y[5], b[6] + y1[6] + y[6], b[7] + y1[7] + y[7]};
            __builtin_nontemporal_store(o0, op);
            __builtin_nontemporal_store(o1, op + 1);
        }
    } else if (row >= USR0 && row < ROWS_EFF) {
        unsigned ur = row - USR0;
        unsigned co = cntoffs[row];
        int n = co >> 22;
        int start = co & 0x3FFFFF;

        float uo[8];
        if (PASS == 1) {
            const float4* up = (const float4*)&u_emb[(size_t)ur * CHN + chb];
            float4 a0 = up[0], a1 = up[1];
            uo[0]=a0.x; uo[1]=a0.y; uo[2]=a0.z; uo[3]=a0.w;
            uo[4]=a1.x; uo[5]=a1.y; uo[6]=a1.z; uo[7]=a1.w;
        } else {
            bf8_unpack(*(const uint4*)(ubfA + (size_t)ur * CHN + chb), uo);
        }

        float dotv[N_FACTORS];
        #pragma unroll
        for (int f = 0; f < N_FACTORS; ++f) {
            const float4* lp = (const float4*)&latent[f * CHN + chb];
            float4 l0 = lp[0], l1 = lp[1];
            float p = uo[0] * l0.x + uo[1] * l0.y + uo[2] * l0.z + uo[3] * l0.w
                    + uo[4] * l1.x + uo[5] * l1.y + uo[6] * l1.z + uo[7] * l1.w;
            p += __shfl_xor(p, 1, 64);
            p += __shfl_xor(p, 2, 64);
            p += __shfl_xor(p, 4, 64);
            dotv[f] = p;
        }
        float m = fmaxf(fmaxf(dotv[0], dotv[1]), fmaxf(dotv[2], dotv[3]));
        float es = 0.f;
        #pragma unroll
        for (int f = 0; f < N_FACTORS; ++f) { dotv[f] = expf(dotv[f] - m); es += dotv[f]; }
        float sinv = 1.f / es;
        float mix[8] = {0.f,0.f,0.f,0.f,0.f,0.f,0.f,0.f};
        #pragma unroll
        for (int f = 0; f < N_FACTORS; ++f) {
            float sc = dotv[f] * sinv;
            const float4* dp = (const float4*)&disenw[f * CHN + chb];
            float4 d0 = dp[0], d1 = dp[1];
            mix[0] += sc * d0.x; mix[1] += sc * d0.y; mix[2] += sc * d0.z; mix[3] += sc * d0.w;
            mix[4] += sc * d1.x; mix[5] += sc * d1.y; mix[6] += sc * d1.z; mix[7] += sc * d1.w;
        }

        int k = 0;
        for (; k + 4 <= n; k += 4) {
            ulonglong2 qa = *(const ulonglong2*)&recsU[start + k];
            ulonglong2 qb = *(const ulonglong2*)&recsU[start + k + 2];
            uint4 g0 = *(const uint4*)(ebf + (size_t)(qa.x & 0x3FFFFu) * CHN + chb);
            uint4 g1 = *(const uint4*)(ebf + (size_t)(qa.y & 0x3FFFFu) * CHN + chb);
            uint4 g2 = *(const uint4*)(ebf + (size_t)(qb.x & 0x3FFFFu) * CHN + chb);
            uint4 g3 = *(const uint4*)(ebf + (size_t)(qb.y & 0x3FFFFu) * CHN + chb);
            fma8v(g0, __uint_as_float((unsigned)(qa.x >> 18)), acc);
            fma8v(g1, __uint_as_float((unsigned)(qa.y >> 18)), acc);
            fma8v(g2, __uint_as_float((unsigned)(qb.x >> 18)), acc);
            fma8v(g3, __uint_as_float((unsigned)(qb.y >> 18)), acc);
        }
        for (; k < n; ++k) {
            unsigned long long q0 = recsU[start + k];
            uint4 g0 = *(const uint4*)(ebf + (size_t)(q0 & 0x3FFFFu) * CHN + chb);
            fma8v(g0, __uint_as_float((unsigned)(q0 >> 18)), acc);
        }
        float ss = 0.f;
        #pragma unroll
        for (int i = 0; i < 8; ++i) { acc[i] *= (1.f + mix[i]); ss += acc[i] * acc[i]; }
        ss += __shfl_xor(ss, 1, 64);
        ss += __shfl_xor(ss, 2, 64);
        ss += __shfl_xor(ss, 4, 64);
        float innv = 1.f / fmaxf(sqrtf(ss), 1e-12f);
        float y[8];
        #pragma unroll
        for (int i = 0; i < 8; ++i) y[i] = acc[i] * innv;
        if (PASS == 1) {
            uint4 pk;
            pk.x = (unsigned)f2bf(y[0]) | ((unsigned)f2bf(y[1]) << 16);
            pk.y = (unsigned)f2bf(y[2]) | ((unsigned)f2bf(y[3]) << 16);
            pk.z = (unsigned)f2bf(y[4]) | ((unsigned)f2bf(y[5]) << 16);
            pk.w = (unsigned)f2bf(y[6]) | ((unsigned)f2bf(y[7]) << 16);
            *(uint4*)(ubf_new + (size_t)ur * CHN + chb) = pk;
        } else {
            const vf4* bp = (const vf4*)&u_emb[(size_t)ur * CHN + chb];
            vf4 b0 = __builtin_nontemporal_load(bp);
            vf4 b1 = __builtin_nontemporal_load(bp + 1);
            vf4* op = (vf4*)&out_usr[(size_t)ur * CHN + chb];
            vf4 o0 = {b0.x + uo[0] + y[0], b0.y + uo[1] + y[1], b0.z + uo[2] + y[2], b0.w + uo[3] + y[3]};
            vf4 o1 = {b1.x + uo[4] + y[4], b1.y + uo[5] + y[5], b1.z + uo[6] + y[6], b1.w + uo[7] + y[7]};
            __builtin_nontemporal_store(o0, op);
            __builtin_nontemporal_store(o1, op + 1);
        }
    }
}

extern "C" void kernel_launch(void* const* d_in, const int* in_sizes, int n_in,
                              void* d_out, int out_size, void* d_ws, size_t ws_size,
                              hipStream_t stream) {
    const float* user_emb   = (const float*)d_in[0];
    const float* entity_emb = (const float*)d_in[1];
    const float* latent_emb = (const float*)d_in[2];
    const float* weight     = (const float*)d_in[3];
    const float* att        = (const float*)d_in[4];
    const float* inter_val  = (const float*)d_in[5];
    const int*   edge_index = (const int*)d_in[6];   // [2][N_EDGES]
    const int*   edge_type  = (const int*)d_in[7];
    const int*   inter_row  = (const int*)d_in[8];
    const int*   inter_col  = (const int*)d_in[9];

    const int* head = edge_index;
    const int* tail = edge_index + N_EDGES;

    float* out_ent = (float*)d_out;                              // [250000*64]
    float* out_usr = out_ent + (size_t)N_ENTITIES * CHN;         // [150000*64]
    float* out_cor = out_usr + (size_t)N_USERS * CHN;            // [1]

    // workspace layout (byte offsets kept 16B-aligned)
    char* ws = (char*)d_ws;
    unsigned short* ebf0   = (unsigned short*)ws;                             // 32,000,000 B
    unsigned short* ebfA   = (unsigned short*)(ws + 32000000);                // 32,000,000 B
    unsigned short* ubfA   = (unsigned short*)(ws + 64000000);                // 19,200,000 B
    unsigned long long* binned = (unsigned long long*)(ws + 83200000);        // NB*RCAP u64 = 25,690,112 B
    unsigned long long* recsU  = (unsigned long long*)(ws + 108890112);       // 147*RCAP_OUT u64 = 9,633,792 B
    unsigned int* recsE    = (unsigned int*)(ws + 118523904);                 // 245*RCAP_OUT u32 = 8,028,160 B
    float* disenw          = (float*)(ws + 126552064);                        // 1,024 B
    unsigned int* cntoffs  = (unsigned int*)(ws + 126553088);                 // NB*BROWS u32 = 1,605,632 B
    int*   bcur            = (int*)(ws + 128158720);                          // NB i

    // ---- bucket cursors = 0 (offset-from-base scheme) ----
    hipMemsetAsync(bcur, 0, NB * sizeof(int), stream);

    // ---- fused build: bin_pass + prep + bf16 conv ----
    build_kernel<<<BIN_BLOCKS + 1 + CONV_BLOCKS, 512, 0, stream>>>(
        head, tail, edge_type, inter_row, inter_col, inter_val,
        bcur, binned, weight, att, disenw, out_cor,
        (const float4*)entity_emb, (ushort4*)ebf0);

    // ---- per-bucket CSR (packed cnt|offs) ----
    bucket_scatter_kernel<<<NB, 512, 0, stream>>>(binned, bcur, recsE, recsU, cntoffs);

    const int hop_blocks = (ROWS_EFF * 8 + 255) / 256;           // 12528

    // ---- hop 1: gather from ebf0 -> compact bf16 state (ebfA, ubfA) ----
    hop_kernel<1><<<hop_blocks, 256, 0, stream>>>(ebf0, recsE, recsU, cntoffs,
                                                  weight, latent_emb, disenw,
                                                  user_emb, nullptr, nullptr,
                                                  ebfA, ubfA, nullptr, nullptr);

    // ---- hop 2: gather from ebfA -> out = base + y1 + y2 ----
    hop_kernel<2><<<hop_blocks, 256, 0, stream>>>(ebfA, recsE, recsU, cntoffs,
                                                  weight, latent_emb, disenw,
                                                  user_emb, ebf0, ubfA,
                                                  nullptr, nullptr, out_ent, out_usr);
}